// Round 25
// baseline (216.533 us; speedup 1.0000x reference)
//
#include <hip/hip_runtime.h>
#include <hip/hip_bf16.h>
#include <math.h>

// TopK router: logits = x @ gate_w^T, softmax, top-2, renormalize.
// M=32768 tokens, K=4096, E=64 experts.
// Outputs (concat, harness reads whole buffer as float32):
//   d_out[0 .. 2M)  : top-2 weights (descending)
//   d_out[2M .. 4M) : top-2 expert indices, stored as float values
//
// R25: the untested cell of {A,B}x{reg,LDS}: A -> registers (plain loads,
// 1-chunk-ahead named double buffer; A has ZERO cross-wave reuse so LDS
// buys nothing), B -> LDS via DMA (genuinely shared by 4 waves). Removes
// 1 GB of A LDS round-trip and takes A-DMA out of the barrier chain.
// vmcnt math (in-order): issue order A(c+1) after bar1, B-stage(c+2) after
// bar2 -> at loop head newer-than-A(c) = Bst(c+1) = 4 -> vmcnt(4) proves
// A(c) AND own-wave B(c); bar1 cross-orders other waves' B segs.
// Carried: TPB=64, k=64 chunks, wave = 16 tok x 64 exp, prep_b packed B,
// K-phase stagger, 4-term MFMA, top-3 + TAU=1e-4 + parallel fp64 refine.

typedef __attribute__((ext_vector_type(8))) short short8;
typedef __attribute__((ext_vector_type(4))) float f32x4;

#define TPB 64      // tokens per block
#define NCH 64      // K/64 chunks
#define TAU 1e-4f
#define LROW 68

__device__ __forceinline__ void cvt8(const f32x4* v, short8* hi, short8* lo) {
    const float* f = reinterpret_cast<const float*>(v);
#pragma unroll
    for (int j = 0; j < 8; ++j) {
        __hip_bfloat16 h = __float2bfloat16(f[j]);
        float r = f[j] - __bfloat162float(h);
        __hip_bfloat16 l = __float2bfloat16(r);
        (*hi)[j] = (short)*reinterpret_cast<unsigned short*>(&h);
        (*lo)[j] = (short)*reinterpret_cast<unsigned short*>(&l);
    }
}

// Pack gw into MFMA-fragment order: entry (nt*8192 + w*64 + ln) = 8 bf16 of
// row nt*16+(ln&15), k = w*32 + (ln>>4)*8.
__global__ void prep_b(const float* __restrict__ gw,
                       short8* __restrict__ bh, short8* __restrict__ bl) {
    const int tid = blockIdx.x * 256 + threadIdx.x;
    const int ln  = tid & 63;
    const int w   = (tid >> 6) & 127;
    const int nt  = tid >> 13;
    const int row = nt * 16 + (ln & 15);
    const int k   = w * 32 + ((ln >> 4) << 3);
    f32x4 v[2];
    v[0] = *reinterpret_cast<const f32x4*>(gw + (long)row * 4096 + k);
    v[1] = *reinterpret_cast<const f32x4*>(gw + (long)row * 4096 + k + 4);
    short8 h, l;
    cvt8(v, &h, &l);
    bh[tid] = h;
    bl[tid] = l;
}

__device__ __forceinline__ void gload16(const void* g, void* l) {
    __builtin_amdgcn_global_load_lds(
        (const __attribute__((address_space(1))) void*)g,
        (__attribute__((address_space(3))) void*)l, 16, 0, 0);
}

// LDS: B only. Per buffer 16KB = 16 segs of 1KB (seg s = wl*8 + nt*2 + hl);
// buf0 @0, buf1 @16384. Per wave per chunk: 4 B-instr (segs wv*4..wv*4+3).
#define STAGE_B(C, BUF) do {                                                  \
    char* bB = BB + (BUF) * 16384;                                            \
    _Pragma("unroll")                                                         \
    for (int i = 0; i < 4; ++i) {                                             \
        const int s  = wv * 4 + i;                                            \
        const int wl = s >> 3, nt = (s >> 1) & 3, hl = s & 1;                 \
        const short8* sp = (hl ? blp : bhp)                                   \
            + ((long)nt * 8192 + (2 * (C) + wl) * 64 + ln);                   \
        gload16(sp, bB + s * 1024 + ln * 16);                                 \
    }                                                                         \
} while (0)

// A registers: 4 f32x4 per chunk (2 windows x 8 floats), named dbuf.
#define LOAD_A(BUF, C) do {                                                   \
    const float* p = pA + (long)(C) * 64;                                     \
    (BUF)[0] = *reinterpret_cast<const f32x4*>(p);                            \
    (BUF)[1] = *reinterpret_cast<const f32x4*>(p + 4);                        \
    (BUF)[2] = *reinterpret_cast<const f32x4*>(p + 32);                       \
    (BUF)[3] = *reinterpret_cast<const f32x4*>(p + 36);                       \
} while (0)

// One iteration: vmcnt(4) [A(c),B(c) done] -> bar1 -> issue A(c+1) ->
// compute(c) -> bar2 -> stage B(c+2).
#define ITER(J, ACUR, ANXT) do {                                              \
    const int c_   = (phase + (J)) & (NCH - 1);                               \
    const int buf_ = (J) & 1;                                                 \
    if ((J) + 1 < NCH) asm volatile("s_waitcnt vmcnt(4)" ::: "memory");       \
    else               asm volatile("s_waitcnt vmcnt(0)" ::: "memory");       \
    __builtin_amdgcn_s_barrier();                                             \
    asm volatile("" ::: "memory");                                            \
    if ((J) + 1 < NCH) LOAD_A(ANXT, (phase + (J) + 1) & (NCH - 1));           \
    __builtin_amdgcn_sched_barrier(0);                                        \
    {                                                                         \
        const char* bB = BB + buf_ * 16384;                                   \
        _Pragma("unroll")                                                     \
        for (int wl = 0; wl < 2; ++wl) {                                      \
            short8 ah, al;                                                    \
            cvt8(&(ACUR)[wl * 2], &ah, &al);                                  \
            _Pragma("unroll")                                                 \
            for (int nt = 0; nt < 4; ++nt) {                                  \
                short8 bhv = *(const short8*)(bB + (wl * 8 + nt * 2 + 0) * 1024 + ln * 16); \
                short8 blv = *(const short8*)(bB + (wl * 8 + nt * 2 + 1) * 1024 + ln * 16); \
                acc[nt] = __builtin_amdgcn_mfma_f32_16x16x32_bf16(ah, bhv, acc[nt], 0, 0, 0); \
                acc[nt] = __builtin_amdgcn_mfma_f32_16x16x32_bf16(ah, blv, acc[nt], 0, 0, 0); \
                acc[nt] = __builtin_amdgcn_mfma_f32_16x16x32_bf16(al, bhv, acc[nt], 0, 0, 0); \
                acc[nt] = __builtin_amdgcn_mfma_f32_16x16x32_bf16(al, blv, acc[nt], 0, 0, 0); \
            }                                                                 \
        }                                                                     \
    }                                                                         \
    __builtin_amdgcn_sched_barrier(0);                                        \
    asm volatile("" ::: "memory");                                            \
    __builtin_amdgcn_s_barrier();                                             \
    asm volatile("" ::: "memory");                                            \
    if ((J) + 2 < NCH) STAGE_B((phase + (J) + 2) & (NCH - 1), buf_);          \
    __builtin_amdgcn_sched_barrier(0);                                        \
} while (0)

__global__ __launch_bounds__(256, 4)
void router_fused(const float* __restrict__ x,
                  const short8* __restrict__ bhp,
                  const short8* __restrict__ blp,
                  const float* __restrict__ gw,
                  float* __restrict__ out,
                  int M, int K) {
    __shared__ __align__(16) char BB[32768];
    __shared__ float Ls[TPB * LROW];
    __shared__ int flags[TPB];
    __shared__ double Ld4[4][64];

    const int t  = threadIdx.x;
    const int wv = t >> 6;                  // wave = m-tile (16 tokens)
    const int ln = t & 63;
    const int fr = ln & 15;
    const int q  = ln >> 4;
    const long tok0 = (long)blockIdx.x * TPB;
    const int phase = blockIdx.x & (NCH - 1);

    // this lane's A row and k-quarter base (fragment layout: 8 contiguous k)
    const float* pA = x + (tok0 + wv * 16 + fr) * (long)K + q * 8;

    f32x4 acc[4];
#pragma unroll
    for (int nt = 0; nt < 4; ++nt) acc[nt] = (f32x4){0.f, 0.f, 0.f, 0.f};

    f32x4 Ae[4], Ao[4];

    // prologue (issue order matters): A(c0) first, then B(c0), B(c1)
    LOAD_A(Ae, phase);
    STAGE_B(phase, 0);
    STAGE_B((phase + 1) & (NCH - 1), 1);

    for (int j = 0; j < NCH; j += 2) {
        ITER(j, Ae, Ao);
        ITER(j + 1, Ao, Ae);
    }

    // ---- epilogue: dump logits (C/D: col=lane&15, row=q*4+r) ----
    __syncthreads();
#pragma unroll
    for (int nt = 0; nt < 4; ++nt)
#pragma unroll
        for (int r = 0; r < 4; ++r)
            Ls[(wv * 16 + q * 4 + r) * LROW + nt * 16 + fr] = acc[nt][r];
    __syncthreads();

    if (t < TPB) {
        const float* row = Ls + (long)t * LROW;
        float m1 = -INFINITY, m2 = -INFINITY, m3 = -INFINITY;
        int i1 = 0, i2 = 0;
#pragma unroll 8
        for (int e = 0; e < 64; ++e) {
            const float v = row[e];
            if (v > m1)      { m3 = m2; m2 = m1; i2 = i1; m1 = v; i1 = e; }
            else if (v > m2) { m3 = m2; m2 = v; i2 = e; }
            else if (v > m3) { m3 = v; }
        }
        const float e2 = expf(m2 - m1);
        const float s  = 1.0f + e2;

        const long g = tok0 + t;
        out[2 * g + 0] = 1.0f / s;
        out[2 * g + 1] = e2 / s;
        float* oi = out + 2 * (long)M;
        oi[2 * g + 0] = (float)i1;
        oi[2 * g + 1] = (float)i2;

        flags[t] = ((m1 - m2) < TAU) | ((m2 - m3) < TAU);
    }
    __syncthreads();

    // ---- fp64 refine, 256 threads cooperate (wave=K-quarter, lane=expert) ----
    for (int tk = 0; tk < TPB; ++tk) {
        if (flags[tk]) {
            const float* xr = x + (tok0 + tk) * (long)K + wv * 1024;
            const float* gr = gw + (long)ln * (long)K + wv * 1024;
            double s0 = 0.0, s1 = 0.0, s2 = 0.0, s3 = 0.0;
            for (int k = 0; k < 1024; k += 4) {
                const f32x4 a = *reinterpret_cast<const f32x4*>(xr + k);
                const f32x4 b = *reinterpret_cast<const f32x4*>(gr + k);
                s0 = fma((double)a.x, (double)b.x, s0);
                s1 = fma((double)a.y, (double)b.y, s1);
                s2 = fma((double)a.z, (double)b.z, s2);
                s3 = fma((double)a.w, (double)b.w, s3);
            }
            Ld4[wv][ln] = (s0 + s1) + (s2 + s3);
            __syncthreads();
            if (t == 0) {
                double m1 = -INFINITY, m2 = -INFINITY;
                int i1 = 0, i2 = 0;
                for (int e = 0; e < 64; ++e) {
                    const double v = Ld4[0][e] + Ld4[1][e] + Ld4[2][e] + Ld4[3][e];
                    if (v > m1)      { m2 = m1; i2 = i1; m1 = v; i1 = e; }
                    else if (v > m2) { m2 = v; i2 = e; }
                }
                const double e2 = exp(m2 - m1);
                const double s  = 1.0 + e2;
                const long g = tok0 + tk;
                out[2 * g + 0] = (float)(1.0 / s);
                out[2 * g + 1] = (float)(e2 / s);
                float* oi = out + 2 * (long)M;
                oi[2 * g + 0] = (float)i1;
                oi[2 * g + 1] = (float)i2;
            }
            __syncthreads();
        }
    }
}

extern "C" void kernel_launch(void* const* d_in, const int* in_sizes, int n_in,
                              void* d_out, int out_size, void* d_ws, size_t ws_size,
                              hipStream_t stream) {
    const float* x  = (const float*)d_in[0];
    const float* gw = (const float*)d_in[1];
    float* out = (float*)d_out;

    const int K = 4096;
    const int M = in_sizes[0] / K;          // 32768 tokens
    const int nblocks = M / TPB;            // 512

    short8* bh = (short8*)d_ws;             // 1 MB packed B
    short8* bl = bh + 32768;

    prep_b<<<128, 256, 0, stream>>>(gw, bh, bl);
    router_fused<<<nblocks, 256, 0, stream>>>(x, bh, bl, gw, out, M, K);
}